// Round 1
// baseline (57.748 us; speedup 1.0000x reference)
//
#include <hip/hip_runtime.h>
#include <math.h>

static constexpr int NPT = 98;
static constexpr int WAVES_PER_BLOCK = 4;
static constexpr float INV_SIGMA = 1.0f / 15.0f;

// Curve layout (WFLW 98-pt): (start A, NSEG = n-1, BASE into segment array)
// M = 2*NSEG per curve; bases: 0,64,80,96,112,126,140,162; total 180 segments.

template<int A, int NSEG, int BASE>
__device__ __forceinline__ void build_segs(const float2* __restrict__ p,
                                           const float2* __restrict__ g,
                                           float4* sg, int lane) {
    constexpr int M = 2 * NSEG;
    if (lane < M) {
        const bool is_g = lane >= NSEG;
        const int k = is_g ? (lane - NSEG) : lane;
        const float2* src = is_g ? g : p;
        float2 a = src[A + k];
        float2 b = src[A + k + 1];
        float cx = 0.5f * (a.x + b.x);
        float cy = 0.5f * (a.y + b.y);
        float tx = b.x - a.x;
        float ty = b.y - a.y;
        if (is_g) { tx = -tx; ty = -ty; }
        sg[BASE + lane] = make_float4(cx, cy, tx, ty);
    }
}

template<int NSEG, int BASE>
__device__ __forceinline__ float pair_acc(const float4* sg, int lane, float acc) {
    constexpr int M = 2 * NSEG;          // segments in this curve
    constexpr int G = 64 / M;            // i-groups packed into one wave
    constexpr int NT = (M + G - 1) / G;  // i-steps per lane
    if (lane < G * M) {
        const int j = lane % M;          // fixed column per lane (register-cached)
        const int q = lane / M;
        float4 sj = sg[BASE + j];
        for (int t = 0; t < NT; ++t) {
            int i = q + G * t;
            if (i < M) {
                float4 si = sg[BASE + i];   // few distinct addrs -> LDS broadcast
                float dx = si.x - sj.x;
                float dy = si.y - sj.y;
                float d2 = dx * dx + dy * dy;
                float dt = si.z * sj.z + si.w * sj.w;
                acc += __expf(-d2 * INV_SIGMA) * dt;
            }
        }
    }
    return acc;
}

__global__ __launch_bounds__(WAVES_PER_BLOCK * 64)
void lddmm_main(const float* __restrict__ pred, const float* __restrict__ gt,
                float* __restrict__ ws, int batch) {
    __shared__ float4 seg[WAVES_PER_BLOCK][184];  // 180 used (+pad)
    const int wave = threadIdx.x >> 6;
    const int lane = threadIdx.x & 63;
    const int b = blockIdx.x * WAVES_PER_BLOCK + wave;
    const bool valid = b < batch;

    const float2* p = (const float2*)(pred + (size_t)b * (2 * NPT));
    const float2* g = (const float2*)(gt + (size_t)b * (2 * NPT));
    float4* sg = seg[wave];

    float dsum = 0.0f;
    if (valid) {
        build_segs<0, 32, 0>(p, g, sg, lane);
        build_segs<33, 8, 64>(p, g, sg, lane);
        build_segs<42, 8, 80>(p, g, sg, lane);
        build_segs<51, 8, 96>(p, g, sg, lane);
        build_segs<60, 7, 112>(p, g, sg, lane);
        build_segs<68, 7, 126>(p, g, sg, lane);
        build_segs<76, 11, 140>(p, g, sg, lane);
        build_segs<88, 9, 162>(p, g, sg, lane);

        // landmark mean-distance partial (global reads, L1-resident)
        for (int t = lane; t < NPT; t += 64) {
            float2 pp = p[t];
            float2 gg = g[t];
            float dx = pp.x - gg.x;
            float dy = pp.y - gg.y;
            dsum += sqrtf(dx * dx + dy * dy);
        }
    }

    __syncthreads();  // uniform across block

    float acc = 0.0f;
    if (valid) {
        acc = pair_acc<32, 0>(sg, lane, acc);
        acc = pair_acc<8, 64>(sg, lane, acc);
        acc = pair_acc<8, 80>(sg, lane, acc);
        acc = pair_acc<8, 96>(sg, lane, acc);
        acc = pair_acc<7, 112>(sg, lane, acc);
        acc = pair_acc<7, 126>(sg, lane, acc);
        acc = pair_acc<11, 140>(sg, lane, acc);
        acc = pair_acc<9, 162>(sg, lane, acc);
    }

    // wave reduction of (dsum, acc)
    for (int off = 32; off >= 1; off >>= 1) {
        dsum += __shfl_xor(dsum, off, 64);
        acc  += __shfl_xor(acc, off, 64);
    }

    if (valid && lane == 0) {
        float2 e0 = g[60];
        float2 e1 = g[72];
        float ex = e0.x - e1.x;
        float ey = e0.y - e1.y;
        float eye = sqrtf(ex * ex + ey * ey);
        // 0.8*mean(dist)/eye + 0.2*acc/(98*eye) == (0.8*dsum + 0.2*acc)/(98*eye)
        ws[b] = (0.8f * dsum + 0.2f * acc) / ((float)NPT * eye);
    }
}

__global__ __launch_bounds__(256)
void lddmm_reduce(const float* __restrict__ ws, float* __restrict__ out, int batch) {
    __shared__ float sm[256];
    const int t = threadIdx.x;
    float s = 0.0f;
    for (int i = t; i < batch; i += 256) s += ws[i];
    sm[t] = s;
    __syncthreads();
    for (int off = 128; off >= 1; off >>= 1) {
        if (t < off) sm[t] += sm[t + off];
        __syncthreads();
    }
    if (t == 0) out[0] = sm[0] * (1.0f / (float)batch);
}

extern "C" void kernel_launch(void* const* d_in, const int* in_sizes, int n_in,
                              void* d_out, int out_size, void* d_ws, size_t ws_size,
                              hipStream_t stream) {
    const float* pred = (const float*)d_in[0];
    const float* gt = (const float*)d_in[1];
    float* out = (float*)d_out;
    float* ws = (float*)d_ws;
    const int batch = in_sizes[0] / (2 * NPT);

    const int grid = (batch + WAVES_PER_BLOCK - 1) / WAVES_PER_BLOCK;
    lddmm_main<<<grid, WAVES_PER_BLOCK * 64, 0, stream>>>(pred, gt, ws, batch);
    lddmm_reduce<<<1, 256, 0, stream>>>(ws, out, batch);
}

// Round 2
// 45.632 us; speedup vs baseline: 1.2655x; 1.2655x over previous
//
#include <hip/hip_runtime.h>
#include <math.h>

static constexpr int NPT = 98;
static constexpr int WPB = 4;           // waves (batch elems) per block
static constexpr int SEGSLOTS = 272;    // 270 used + 2 zero pad
static constexpr float CSCALE = 0.310128480f;  // sqrt(log2(e)/15)

#if __has_builtin(__builtin_amdgcn_exp2f)
#define EXP2F(x) __builtin_amdgcn_exp2f(x)
#else
#define EXP2F(x) exp2f(x)
#endif

// LDS layout per wave (float4 slots): each curve gets M + M/2 slots
// (M segments + duplicate of first M/2 for wrap-free circulant reads).
//  c0: base   0, M=64  -> [0,96)
//  c1: base  96, M=16  -> [96,120)
//  c2: base 120, M=16  -> [120,144)
//  c3: base 144, M=16  -> [144,168)
//  c4: base 168, M=14  -> [168,189)
//  c5: base 189, M=14  -> [189,210)
//  c6: base 210, M=22  -> [210,243)
//  c7: base 243, M=18  -> [243,270)

__device__ __forceinline__ float pair_term(float4 si, float4 sj) {
    float dx = si.x - sj.x;
    float dy = si.y - sj.y;
    float d2s = dx * dx + dy * dy;           // already scaled by log2e/sigma
    float dt = si.z * sj.z + si.w * sj.w;
    return EXP2F(-d2s) * dt;
}

__global__ __launch_bounds__(WPB * 64)
void lddmm_main(const float* __restrict__ pred, const float* __restrict__ gt,
                float* __restrict__ ws, int batch) {
    __shared__ float4 seg[WPB][SEGSLOTS];
    __shared__ float part[WPB];
    const int wave = threadIdx.x >> 6;
    const int lane = threadIdx.x & 63;
    const int b = blockIdx.x * WPB + wave;
    const bool valid = b < batch;
    const int brow = valid ? b : 0;

    const float2* p = (const float2*)(pred + (size_t)brow * (2 * NPT));
    const float2* g = (const float2*)(gt + (size_t)brow * (2 * NPT));
    float4* sg = seg[wave];

    float accS = 0.0f;   // x1 bucket: diag + t=M/2 terms + phase-B (m applied)
    float accD = 0.0f;   // x2 bucket: phase-A t=1..31
    float dsum = 0.0f;

    // ---- staging: build 180 segments (+ dup of first halves), 3 passes
    #pragma unroll
    for (int pass = 0; pass < 3; ++pass) {
        int s = lane + 64 * pass;
        if (s < 180) {
            int A, NS, B, rel;
            if (s < 64)       { A = 0;  NS = 32; B = 0;   rel = s; }
            else if (s < 80)  { A = 33; NS = 8;  B = 96;  rel = s - 64; }
            else if (s < 96)  { A = 42; NS = 8;  B = 120; rel = s - 80; }
            else if (s < 112) { A = 51; NS = 8;  B = 144; rel = s - 96; }
            else if (s < 126) { A = 60; NS = 7;  B = 168; rel = s - 112; }
            else if (s < 140) { A = 68; NS = 7;  B = 189; rel = s - 126; }
            else if (s < 162) { A = 76; NS = 11; B = 210; rel = s - 140; }
            else              { A = 88; NS = 9;  B = 243; rel = s - 162; }
            bool isg = rel >= NS;
            int a = A + (isg ? rel - NS : rel);
            const float2* src = isg ? g : p;
            float2 q0 = src[a];
            float2 q1 = src[a + 1];
            float cx = 0.5f * (q0.x + q1.x) * CSCALE;
            float cy = 0.5f * (q0.y + q1.y) * CSCALE;
            float tx = q1.x - q0.x;
            float ty = q1.y - q0.y;
            if (isg) { tx = -tx; ty = -ty; }
            float4 v = make_float4(cx, cy, tx, ty);
            sg[B + rel] = v;
            if (!isg) sg[B + 2 * NS + rel] = v;   // dup first half (p-segs)
            accS += tx * tx + ty * ty;            // diagonal: w=1, dot=|tau|^2
        }
    }
    if (lane < 2) sg[270 + lane] = make_float4(0.f, 0.f, 0.f, 0.f);

    // ---- landmark mean distance
    #pragma unroll
    for (int pass = 0; pass < 2; ++pass) {
        int t = lane + 64 * pass;
        if (t < NPT) {
            float2 pp = p[t];
            float2 gg = g[t];
            float dx = pp.x - gg.x;
            float dy = pp.y - gg.y;
            dsum += sqrtf(dx * dx + dy * dy);
        }
    }

    __syncthreads();

    // ---- phase A: curve 0 (M=64), circulant symmetric, wrap-free via dup
    {
        const float4* sp = sg + lane;
        float4 sj = sp[0];
        #pragma unroll
        for (int t = 1; t <= 31; ++t) accD += pair_term(sp[t], sj);  // x2
        accS += pair_term(sp[32], sj);                               // x1
    }

    // ---- phase B plan 1: curves c1,c2,c3 (M=16) + c4 (M=14), t=1..8
    {
        int addr; float hp1;
        if (lane < 16)      { addr = 96 + lane;         hp1 = 9.f; }
        else if (lane < 32) { addr = 120 + (lane - 16); hp1 = 9.f; }
        else if (lane < 48) { addr = 144 + (lane - 32); hp1 = 9.f; }
        else if (lane < 62) { addr = 168 + (lane - 48); hp1 = 8.f; }
        else                { addr = 0;                 hp1 = 0.f; }
        const float4* sp = sg + addr;
        float4 sj = sp[0];
        #pragma unroll
        for (int t = 1; t <= 8; ++t) {
            // m = 2 for t<half, 1 for t==half, 0 past the end (med3 clamp)
            float m = fminf(fmaxf(hp1 - (float)t, 0.f), 2.f);
            accS = fmaf(m, pair_term(sp[t], sj), accS);
        }
    }

    // ---- phase B plan 2: c5 (M=14), c6 (M=22), c7 (M=18), t=1..11
    {
        int addr; float hp1;
        if (lane < 14)      { addr = 189 + lane;        hp1 = 8.f;  }
        else if (lane < 36) { addr = 210 + (lane - 14); hp1 = 12.f; }
        else if (lane < 54) { addr = 243 + (lane - 36); hp1 = 10.f; }
        else                { addr = 0;                 hp1 = 0.f;  }
        const float4* sp = sg + addr;
        float4 sj = sp[0];
        #pragma unroll
        for (int t = 1; t <= 11; ++t) {
            float m = fminf(fmaxf(hp1 - (float)t, 0.f), 2.f);
            accS = fmaf(m, pair_term(sp[t], sj), accS);
        }
    }

    // linear combine per lane, then a single wave reduction
    float v = 0.8f * dsum + 0.2f * (accS + 2.0f * accD);
    #pragma unroll
    for (int off = 32; off >= 1; off >>= 1) v += __shfl_xor(v, off, 64);

    if (lane == 0) {
        float2 e0 = g[60];
        float2 e1 = g[72];
        float ex = e0.x - e1.x;
        float ey = e0.y - e1.y;
        float eye = sqrtf(ex * ex + ey * ey);
        part[wave] = valid ? v / ((float)NPT * eye) : 0.0f;
    }
    __syncthreads();
    if (threadIdx.x == 0)
        ws[blockIdx.x] = part[0] + part[1] + part[2] + part[3];
}

__global__ __launch_bounds__(256)
void lddmm_reduce(const float* __restrict__ ws, float* __restrict__ out,
                  int n, float invbatch) {
    __shared__ float sm[256];
    const int t = threadIdx.x;
    float s = 0.0f;
    for (int i = t; i < n; i += 256) s += ws[i];
    sm[t] = s;
    __syncthreads();
    for (int off = 128; off >= 1; off >>= 1) {
        if (t < off) sm[t] += sm[t + off];
        __syncthreads();
    }
    if (t == 0) out[0] = sm[0] * invbatch;
}

extern "C" void kernel_launch(void* const* d_in, const int* in_sizes, int n_in,
                              void* d_out, int out_size, void* d_ws, size_t ws_size,
                              hipStream_t stream) {
    const float* pred = (const float*)d_in[0];
    const float* gt = (const float*)d_in[1];
    float* out = (float*)d_out;
    float* ws = (float*)d_ws;
    const int batch = in_sizes[0] / (2 * NPT);

    const int nblk = (batch + WPB - 1) / WPB;
    lddmm_main<<<nblk, WPB * 64, 0, stream>>>(pred, gt, ws, batch);
    lddmm_reduce<<<1, 256, 0, stream>>>(ws, out, nblk, 1.0f / (float)batch);
}